// Round 5
// baseline (1448.291 us; speedup 1.0000x reference)
//
#include <hip/hip_runtime.h>
#include <cstddef>

#define NN 10240
#define NE (NN * 32)
#define DD 128
#define MIS_ITERS 40

// output layout (float32 elements)
#define OFF_OUT ((size_t)0)
#define OFF_ADJ ((size_t)NN * DD)
#define OFF_MIS (OFF_ADJ + (size_t)NN * (size_t)NN)
#define OFF_CL  (OFF_MIS + (size_t)NN)

// ---------------- init ----------------
__global__ void k_init(int* rcnt, int* cursor, int* misA, int* covA, int* nbA,
                       int* unc, int* one_, float* cntF) {
  int v = blockIdx.x * blockDim.x + threadIdx.x;
  if (v < NN) {
    rcnt[v] = 0; cursor[v] = 0; misA[v] = 0; covA[v] = 0; nbA[v] = NN;
    cntF[v] = 0.0f;
  }
  if (v < MIS_ITERS) unc[v] = 0;
  if (v == 0) one_[0] = 1;
}

// ---------------- CSR build (stable by edge id) ----------------
__global__ void k_hist(const int* __restrict__ rowA, int* __restrict__ rcnt) {
  int e = blockIdx.x * blockDim.x + threadIdx.x;
  if (e < NE) atomicAdd(&rcnt[rowA[e]], 1);
}

__global__ void k_scan(const int* __restrict__ rcnt, int* __restrict__ rptr) {
  __shared__ int part[1024];
  int t = threadIdx.x;
  int local[10];
  int sum = 0;
  for (int k = 0; k < 10; k++) { local[k] = sum; sum += rcnt[t * 10 + k]; }
  part[t] = sum;
  __syncthreads();
  for (int off = 1; off < 1024; off <<= 1) {
    int v = (t >= off) ? part[t - off] : 0;
    __syncthreads();
    part[t] += v;
    __syncthreads();
  }
  int base = (t == 0) ? 0 : part[t - 1];
  for (int k = 0; k < 10; k++) rptr[t * 10 + k] = base + local[k];
  if (t == 1023) rptr[NN] = part[1023];
}

__global__ void k_fill(const int* __restrict__ rowA, const int* __restrict__ rptr,
                       int* __restrict__ cursor, int* __restrict__ ebuf) {
  int e = blockIdx.x * blockDim.x + threadIdx.x;
  if (e >= NE) return;
  int r = rowA[e];
  int p = atomicAdd(&cursor[r], 1);
  ebuf[rptr[r] + p] = e;
}

// sort row segment by e (stable order for deg sum), compute deg in e-order,
// then stable-sort by col (keeps e-order within equal col) for bucket walk.
__global__ void k_rowprep(int* __restrict__ ebuf, const int* __restrict__ rptr,
                          const int* __restrict__ colA, const float* __restrict__ attr,
                          float* __restrict__ degA) {
  int v = blockIdx.x * blockDim.x + threadIdx.x;
  if (v >= NN) return;
  int s = rptr[v], t = rptr[v + 1];
  // insertion sort ascending by edge id
  for (int i = s + 1; i < t; i++) {
    int key = ebuf[i];
    int j = i - 1;
    while (j >= s && ebuf[j] > key) { ebuf[j + 1] = ebuf[j]; j--; }
    ebuf[j + 1] = key;
  }
  // sequential f32 degree sum in edge-id order (replicates scatter-add order)
  float dsum = 0.0f;
  for (int i = s; i < t; i++) dsum += attr[ebuf[i]];
  degA[v] = dsum;
  // stable insertion sort by col (strict > keeps equal-col e-order)
  for (int i = s + 1; i < t; i++) {
    int key = ebuf[i];
    int kc = colA[key];
    int j = i - 1;
    while (j >= s && colA[ebuf[j]] > kc) { ebuf[j + 1] = ebuf[j]; j--; }
    ebuf[j + 1] = key;
  }
}

// ---------------- MIS iteration (integer-exact) ----------------
__global__ void k_emin(const int* __restrict__ gate, const int* __restrict__ rowA,
                       const int* __restrict__ colA, const int* __restrict__ covA,
                       const int* __restrict__ rank, int* __restrict__ nbA) {
  if (*gate == 0) return;
  int e = blockIdx.x * blockDim.x + threadIdx.x;
  if (e >= NE) return;
  int r = rowA[e];
  if (covA[r]) return;
  atomicMin(&nbA[colA[e]], rank[r]);
}

__global__ void k_node1(const int* __restrict__ gate, const int* __restrict__ rank,
                        int* __restrict__ nbA, int* __restrict__ misA,
                        int* __restrict__ covA, int* __restrict__ unc_i) {
  if (*gate == 0) return;
  int v = blockIdx.x * blockDim.x + threadIdx.x;
  if (v >= NN) return;
  int cov = covA[v];
  int nb = nbA[v];
  nbA[v] = NN;  // re-init for next iteration
  int mr0 = cov ? NN : rank[v];
  int m = min(nb, mr0);
  int mi = misA[v];
  if (rank[v] == m) mi = 1;
  misA[v] = mi;
  int c2 = cov | mi;
  covA[v] = c2;
  if (!c2) atomicAdd(unc_i, 1);  // conservative (pre-ecov) convergence count
}

__global__ void k_ecov(const int* __restrict__ gate, const int* __restrict__ rowA,
                       const int* __restrict__ colA, const int* __restrict__ misA,
                       int* __restrict__ covA) {
  if (*gate == 0) return;
  int e = blockIdx.x * blockDim.x + threadIdx.x;
  if (e >= NE) return;
  if (misA[rowA[e]]) covA[colA[e]] = 1;  // idempotent store
}

// ---------------- per-row multinomial cluster (f32-order-faithful) ----------------
// MODE 0: raw bucket rowsum.  MODE 1: cumsum of normalized -> cdf_last.
// MODE 2: first bucket with cdf > thr.
template <int MODE>
__device__ float walk_row(int v, int s, int t, const int* __restrict__ ebuf,
                          const int* __restrict__ colA, const float* __restrict__ attr,
                          const int* __restrict__ misA, float dsafe, int misv,
                          float rs_safe, float thr, int* outc) {
  int i = s;
  int sp = misv;  // self-loop (EPS at col v) pending
  float cum = 0.0f;
  while (i < t || sp) {
    int bc;
    if (i < t) {
      int c = colA[ebuf[i]];
      bc = (sp && v <= c) ? v : c;
    } else {
      bc = v;
    }
    float b = 0.0f;
    while (i < t) {
      int e = ebuf[i];
      int c = colA[e];
      if (c != bc) break;
      if (misA[c]) b += (0.5f * attr[e]) / dsafe;  // rw_val, e-ascending
      i++;
    }
    if (sp && bc == v) { b += 0.5f; sp = 0; }  // EPS self-loop appended last
    if (MODE == 0) {
      cum += b;
    } else {
      float nv = b / rs_safe;
      cum += nv;
      if (MODE == 2 && cum > thr) { *outc = bc; return cum; }
    }
  }
  return cum;
}

__global__ void k_cluster(const int* __restrict__ rptr, const int* __restrict__ ebuf,
                          const int* __restrict__ colA, const float* __restrict__ attr,
                          const float* __restrict__ degA, const int* __restrict__ misA,
                          const float* __restrict__ u, int* __restrict__ clA) {
  int v = blockIdx.x * blockDim.x + threadIdx.x;
  if (v >= NN) return;
  int s = rptr[v], t = rptr[v + 1];
  float degv = degA[v];
  float dsafe = (degv == 0.0f) ? 1.0f : degv;
  int misv = misA[v];
  int dummy = 0;
  float rs = walk_row<0>(v, s, t, ebuf, colA, attr, misA, dsafe, misv, 1.0f, 0.0f, &dummy);
  float rs_safe = (rs == 0.0f) ? 1.0f : rs;
  float last = walk_row<1>(v, s, t, ebuf, colA, attr, misA, dsafe, misv, rs_safe, 0.0f, &dummy);
  float thr = u[v] * last;
  int c = 0;
  walk_row<2>(v, s, t, ebuf, colA, attr, misA, dsafe, misv, rs_safe, thr, &c);
  clA[v] = c;
}

// ---------------- outputs ----------------
__global__ void k_final(const int* __restrict__ misA, const int* __restrict__ clA,
                        float* __restrict__ outF, float* __restrict__ cntF) {
  int v = blockIdx.x * blockDim.x + threadIdx.x;
  if (v >= NN) return;
  outF[OFF_MIS + v] = misA[v] ? 1.0f : 0.0f;
  outF[OFF_CL + v] = (float)clA[v];
  atomicAdd(&cntF[clA[v]], 1.0f);
}

__global__ void k_pool(const float* __restrict__ x, const int* __restrict__ clA,
                       float* __restrict__ outF) {
  int idx = blockIdx.x * blockDim.x + threadIdx.x;
  if (idx >= NN * DD) return;
  int v = idx >> 7;
  int d = idx & 127;
  atomicAdd(&outF[OFF_OUT + (size_t)clA[v] * DD + d], x[idx]);
}

__global__ void k_div(const float* __restrict__ cntF, float* __restrict__ outF) {
  int idx = blockIdx.x * blockDim.x + threadIdx.x;
  if (idx >= NN * DD) return;
  int v = idx >> 7;
  outF[OFF_OUT + idx] = outF[OFF_OUT + idx] / fmaxf(cntF[v], 1.0f);
}

__global__ void k_adj(const int* __restrict__ rowA, const int* __restrict__ colA,
                      const float* __restrict__ attr, const int* __restrict__ clA,
                      float* __restrict__ outF) {
  int e = blockIdx.x * blockDim.x + threadIdx.x;
  if (e >= NE) return;
  int cr = clA[rowA[e]];
  int cc = clA[colA[e]];
  atomicAdd(&outF[OFF_ADJ + (size_t)cr * NN + cc], attr[e]);
}

extern "C" void kernel_launch(void* const* d_in, const int* in_sizes, int n_in,
                              void* d_out, int out_size, void* d_ws, size_t ws_size,
                              hipStream_t stream) {
  const float* x    = (const float*)d_in[0];
  const float* attr = (const float*)d_in[1];
  const float* u    = (const float*)d_in[2];
  const int*   ei   = (const int*)d_in[3];
  const int*   rank = (const int*)d_in[4];
  const int* rowA = ei;
  const int* colA = ei + NE;
  float* outF = (float*)d_out;

  // workspace layout (4B elements)
  int* rcnt   = (int*)d_ws;          // NN
  int* cursor = rcnt + NN;           // NN
  int* rptr   = cursor + NN;         // NN+1
  int* ebuf   = rptr + NN + 1;       // NE
  int* misA   = ebuf + NE;           // NN
  int* covA   = misA + NN;           // NN
  int* nbA    = covA + NN;           // NN
  int* clA    = nbA + NN;            // NN
  int* unc    = clA + NN;            // MIS_ITERS
  int* one_   = unc + MIS_ITERS;     // 1
  float* degA = (float*)(one_ + 1);  // NN
  float* cntF = degA + NN;           // NN

  hipMemsetAsync(d_out, 0, (size_t)out_size * sizeof(float), stream);

  dim3 blk(256);
  dim3 gN((NN + 255) / 256);
  dim3 gE((NE + 255) / 256);
  dim3 gND((NN * DD + 255) / 256);

  k_init<<<gN, blk, 0, stream>>>(rcnt, cursor, misA, covA, nbA, unc, one_, cntF);
  k_hist<<<gE, blk, 0, stream>>>(rowA, rcnt);
  k_scan<<<1, 1024, 0, stream>>>(rcnt, rptr);
  k_fill<<<gE, blk, 0, stream>>>(rowA, rptr, cursor, ebuf);
  k_rowprep<<<gN, blk, 0, stream>>>(ebuf, rptr, colA, attr, degA);

  for (int i = 0; i < MIS_ITERS; i++) {
    const int* gate = (i == 0) ? one_ : (unc + (i - 1));
    k_emin<<<gE, blk, 0, stream>>>(gate, rowA, colA, covA, rank, nbA);
    k_node1<<<gN, blk, 0, stream>>>(gate, rank, nbA, misA, covA, unc + i);
    k_ecov<<<gE, blk, 0, stream>>>(gate, rowA, colA, misA, covA);
  }

  k_cluster<<<gN, blk, 0, stream>>>(rptr, ebuf, colA, attr, degA, misA, u, clA);
  k_final<<<gN, blk, 0, stream>>>(misA, clA, outF, cntF);
  k_pool<<<gND, blk, 0, stream>>>(x, clA, outF);
  k_div<<<gND, blk, 0, stream>>>(cntF, outF);
  k_adj<<<gE, blk, 0, stream>>>(rowA, colA, attr, clA, outF);
}

// Round 8
// 954.370 us; speedup vs baseline: 1.5175x; 1.5175x over previous
//
#include <hip/hip_runtime.h>
#include <cstddef>

#define NN 10240
#define NE (NN * 32)
#define DD 128
#define MIS_ITERS 40
#define MAXD 128

// output layout (float32 elements)
#define OFF_OUT ((size_t)0)
#define OFF_ADJ ((size_t)NN * DD)
#define OFF_MIS (OFF_ADJ + (size_t)NN * (size_t)NN)
#define OFF_CL  (OFF_MIS + (size_t)NN)

// ---------------- init ----------------
__global__ void k_init(int* rcnt, int* cursor, int* misA, int* covA, int* nbA,
                       int* unc, int* one_, float* cntF) {
  int v = blockIdx.x * blockDim.x + threadIdx.x;
  if (v < NN) {
    rcnt[v] = 0; cursor[v] = 0; misA[v] = 0; covA[v] = 0; nbA[v] = NN;
    cntF[v] = 0.0f;
  }
  if (v < MIS_ITERS) unc[v] = 0;
  if (v == 0) one_[0] = 1;
}

// ---------------- CSR build (stable by edge id) ----------------
__global__ void k_hist(const int* __restrict__ rowA, int* __restrict__ rcnt) {
  int e = blockIdx.x * blockDim.x + threadIdx.x;
  if (e < NE) atomicAdd(&rcnt[rowA[e]], 1);
}

__global__ void k_scan(const int* __restrict__ rcnt, int* __restrict__ rptr) {
  __shared__ int part[1024];
  int t = threadIdx.x;
  int local[10];
  int sum = 0;
  for (int k = 0; k < 10; k++) { local[k] = sum; sum += rcnt[t * 10 + k]; }
  part[t] = sum;
  __syncthreads();
  for (int off = 1; off < 1024; off <<= 1) {
    int v = (t >= off) ? part[t - off] : 0;
    __syncthreads();
    part[t] += v;
    __syncthreads();
  }
  int base = (t == 0) ? 0 : part[t - 1];
  for (int k = 0; k < 10; k++) rptr[t * 10 + k] = base + local[k];
  if (t == 1023) rptr[NN] = part[1023];
}

__global__ void k_fill(const int* __restrict__ rowA, const int* __restrict__ rptr,
                       int* __restrict__ cursor, int* __restrict__ ebuf) {
  int e = blockIdx.x * blockDim.x + threadIdx.x;
  if (e >= NE) return;
  int r = rowA[e];
  int p = atomicAdd(&cursor[r], 1);
  ebuf[rptr[r] + p] = e;
}

// ---------------- rowprep: one wave per row, register bitonic sorts ----------------
// Replaces per-thread global-memory insertion sorts (555us, latency-bound,
// occupancy 1.6%) with wave-parallel shuffle bitonic. Semantics preserved:
//  sort1 by e (u32)  -> f32 degree sum in exact np.add.at order
//  sort2 by (col<<19)|e (u64 unique key) == stable col sort of e-sorted list
__device__ inline unsigned long long shfl_xor_u64(unsigned long long x, int m) {
  int lo = (int)(unsigned)(x & 0xFFFFFFFFull);
  int hi = (int)(unsigned)(x >> 32);
  lo = __shfl_xor(lo, m);
  hi = __shfl_xor(hi, m);
  return (((unsigned long long)(unsigned)hi) << 32) | (unsigned)lo;
}

__global__ void k_rowprep(int* __restrict__ ebuf, const int* __restrict__ rptr,
                          const int* __restrict__ colA, const float* __restrict__ attr,
                          float* __restrict__ degA) {
  int lane = threadIdx.x & 63;
  int v = blockIdx.x * (blockDim.x >> 6) + (threadIdx.x >> 6);
  if (v >= NN) return;
  int s = rptr[v], t = rptr[v + 1];
  int d = t - s;

  if (d > MAXD) {  // exact fallback (never expected at this input scale)
    if (lane == 0) {
      for (int i = s + 1; i < t; i++) {
        int key = ebuf[i];
        int j = i - 1;
        while (j >= s && ebuf[j] > key) { ebuf[j + 1] = ebuf[j]; j--; }
        ebuf[j + 1] = key;
      }
      float dsum = 0.0f;
      for (int i = s; i < t; i++) dsum += attr[ebuf[i]];
      degA[v] = dsum;
      for (int i = s + 1; i < t; i++) {
        int key = ebuf[i];
        int kc = colA[key];
        int j = i - 1;
        while (j >= s && colA[ebuf[j]] > kc) { ebuf[j + 1] = ebuf[j]; j--; }
        ebuf[j + 1] = key;
      }
    }
    return;
  }

  // element index i = lane + 64*r, r in {0,1}; pad with UINT_MAX
  unsigned e0 = (lane < d) ? (unsigned)ebuf[s + lane] : 0xFFFFFFFFu;
  unsigned e1 = (lane + 64 < d) ? (unsigned)ebuf[s + 64 + lane] : 0xFFFFFFFFu;

  // ---- bitonic sort 128 x u32 ascending (sort by edge id) ----
  for (int k = 2; k <= 128; k <<= 1) {
    for (int j = k >> 1; j >= 1; j >>= 1) {
      if (j >= 64) {  // only k=128: cross-r compare within lane, ascending
        unsigned lo = min(e0, e1), hi = max(e0, e1);
        e0 = lo; e1 = hi;
      } else {
        unsigned p0 = (unsigned)__shfl_xor((int)e0, j);
        unsigned p1 = (unsigned)__shfl_xor((int)e1, j);
        bool low = ((lane & j) == 0);
        bool up0 = ((lane & k) == 0);
        bool up1 = (((lane + 64) & k) == 0);
        e0 = (low == up0) ? min(e0, p0) : max(e0, p0);
        e1 = (low == up1) ? min(e1, p1) : max(e1, p1);
      }
    }
  }

  // ---- degree: sequential f32 sum in e-ascending order (np.add.at order) ----
  float a0 = (lane < d) ? attr[e0] : 0.0f;
  float a1 = (lane + 64 < d) ? attr[e1] : 0.0f;
  float dsum = 0.0f;
  for (int i = 0; i < d; i++) {
    float ai = (i < 64) ? __shfl(a0, i) : __shfl(a1, i - 64);
    dsum += ai;
  }
  if (lane == 0) degA[v] = dsum;

  // ---- bitonic sort 128 x u64 by (col<<19)|e  == stable-by-col of e-sorted ----
  unsigned long long k0 = (lane < d)
      ? ((((unsigned long long)(unsigned)colA[e0]) << 19) | (unsigned long long)e0)
      : ~0ull;
  unsigned long long k1 = (lane + 64 < d)
      ? ((((unsigned long long)(unsigned)colA[e1]) << 19) | (unsigned long long)e1)
      : ~0ull;
  for (int k = 2; k <= 128; k <<= 1) {
    for (int j = k >> 1; j >= 1; j >>= 1) {
      if (j >= 64) {
        unsigned long long lo = (k0 < k1) ? k0 : k1;
        unsigned long long hi = (k0 < k1) ? k1 : k0;
        k0 = lo; k1 = hi;
      } else {
        unsigned long long p0 = shfl_xor_u64(k0, j);
        unsigned long long p1 = shfl_xor_u64(k1, j);
        bool low = ((lane & j) == 0);
        bool up0 = ((lane & k) == 0);
        bool up1 = (((lane + 64) & k) == 0);
        unsigned long long n0 = (low == up0) ? ((k0 < p0) ? k0 : p0) : ((k0 < p0) ? p0 : k0);
        unsigned long long n1 = (low == up1) ? ((k1 < p1) ? k1 : p1) : ((k1 < p1) ? p1 : k1);
        k0 = n0; k1 = n1;
      }
    }
  }
  if (lane < d)      ebuf[s + lane]      = (int)(k0 & 0x7FFFFull);
  if (lane + 64 < d) ebuf[s + 64 + lane] = (int)(k1 & 0x7FFFFull);
}

// ---------------- MIS iteration (integer-exact) ----------------
__global__ void k_emin(const int* __restrict__ gate, const int* __restrict__ rowA,
                       const int* __restrict__ colA, const int* __restrict__ covA,
                       const int* __restrict__ rank, int* __restrict__ nbA) {
  if (*gate == 0) return;
  int e = blockIdx.x * blockDim.x + threadIdx.x;
  if (e >= NE) return;
  int r = rowA[e];
  if (covA[r]) return;
  atomicMin(&nbA[colA[e]], rank[r]);
}

__global__ void k_node1(const int* __restrict__ gate, const int* __restrict__ rank,
                        int* __restrict__ nbA, int* __restrict__ misA,
                        int* __restrict__ covA, int* __restrict__ unc_i) {
  if (*gate == 0) return;
  int v = blockIdx.x * blockDim.x + threadIdx.x;
  if (v >= NN) return;
  int cov = covA[v];
  int nb = nbA[v];
  nbA[v] = NN;  // re-init for next iteration
  int mr0 = cov ? NN : rank[v];
  int m = min(nb, mr0);
  int mi = misA[v];
  if (rank[v] == m) mi = 1;
  misA[v] = mi;
  int c2 = cov | mi;
  covA[v] = c2;
  if (!c2) atomicAdd(unc_i, 1);  // conservative (pre-ecov) convergence count
}

__global__ void k_ecov(const int* __restrict__ gate, const int* __restrict__ rowA,
                       const int* __restrict__ colA, const int* __restrict__ misA,
                       int* __restrict__ covA) {
  if (*gate == 0) return;
  int e = blockIdx.x * blockDim.x + threadIdx.x;
  if (e >= NE) return;
  if (misA[rowA[e]]) covA[colA[e]] = 1;  // idempotent store
}

// ---------------- per-row multinomial cluster (f32-order-faithful) ----------------
// MODE 0: raw bucket rowsum.  MODE 1: cumsum of normalized -> cdf_last.
// MODE 2: first bucket with cdf > thr.
template <int MODE>
__device__ float walk_row(int v, int s, int t, const int* __restrict__ ebuf,
                          const int* __restrict__ colA, const float* __restrict__ attr,
                          const int* __restrict__ misA, float dsafe, int misv,
                          float rs_safe, float thr, int* outc) {
  int i = s;
  int sp = misv;  // self-loop (EPS at col v) pending
  float cum = 0.0f;
  while (i < t || sp) {
    int bc;
    if (i < t) {
      int c = colA[ebuf[i]];
      bc = (sp && v <= c) ? v : c;
    } else {
      bc = v;
    }
    float b = 0.0f;
    while (i < t) {
      int e = ebuf[i];
      int c = colA[e];
      if (c != bc) break;
      if (misA[c]) b += (0.5f * attr[e]) / dsafe;  // rw_val, e-ascending
      i++;
    }
    if (sp && bc == v) { b += 0.5f; sp = 0; }  // EPS self-loop appended last
    if (MODE == 0) {
      cum += b;
    } else {
      float nv = b / rs_safe;
      cum += nv;
      if (MODE == 2 && cum > thr) { *outc = bc; return cum; }
    }
  }
  return cum;
}

__global__ void k_cluster(const int* __restrict__ rptr, const int* __restrict__ ebuf,
                          const int* __restrict__ colA, const float* __restrict__ attr,
                          const float* __restrict__ degA, const int* __restrict__ misA,
                          const float* __restrict__ u, int* __restrict__ clA) {
  int v = blockIdx.x * blockDim.x + threadIdx.x;
  if (v >= NN) return;
  int s = rptr[v], t = rptr[v + 1];
  float degv = degA[v];
  float dsafe = (degv == 0.0f) ? 1.0f : degv;
  int misv = misA[v];
  int dummy = 0;
  float rs = walk_row<0>(v, s, t, ebuf, colA, attr, misA, dsafe, misv, 1.0f, 0.0f, &dummy);
  float rs_safe = (rs == 0.0f) ? 1.0f : rs;
  float last = walk_row<1>(v, s, t, ebuf, colA, attr, misA, dsafe, misv, rs_safe, 0.0f, &dummy);
  float thr = u[v] * last;
  int c = 0;
  walk_row<2>(v, s, t, ebuf, colA, attr, misA, dsafe, misv, rs_safe, thr, &c);
  clA[v] = c;
}

// ---------------- outputs ----------------
__global__ void k_final(const int* __restrict__ misA, const int* __restrict__ clA,
                        float* __restrict__ outF, float* __restrict__ cntF) {
  int v = blockIdx.x * blockDim.x + threadIdx.x;
  if (v >= NN) return;
  outF[OFF_MIS + v] = misA[v] ? 1.0f : 0.0f;
  outF[OFF_CL + v] = (float)clA[v];
  atomicAdd(&cntF[clA[v]], 1.0f);
}

__global__ void k_pool(const float* __restrict__ x, const int* __restrict__ clA,
                       float* __restrict__ outF) {
  int idx = blockIdx.x * blockDim.x + threadIdx.x;
  if (idx >= NN * DD) return;
  int v = idx >> 7;
  int d = idx & 127;
  atomicAdd(&outF[OFF_OUT + (size_t)clA[v] * DD + d], x[idx]);
}

__global__ void k_div(const float* __restrict__ cntF, float* __restrict__ outF) {
  int idx = blockIdx.x * blockDim.x + threadIdx.x;
  if (idx >= NN * DD) return;
  int v = idx >> 7;
  outF[OFF_OUT + idx] = outF[OFF_OUT + idx] / fmaxf(cntF[v], 1.0f);
}

__global__ void k_adj(const int* __restrict__ rowA, const int* __restrict__ colA,
                      const float* __restrict__ attr, const int* __restrict__ clA,
                      float* __restrict__ outF) {
  int e = blockIdx.x * blockDim.x + threadIdx.x;
  if (e >= NE) return;
  int cr = clA[rowA[e]];
  int cc = clA[colA[e]];
  atomicAdd(&outF[OFF_ADJ + (size_t)cr * NN + cc], attr[e]);
}

extern "C" void kernel_launch(void* const* d_in, const int* in_sizes, int n_in,
                              void* d_out, int out_size, void* d_ws, size_t ws_size,
                              hipStream_t stream) {
  const float* x    = (const float*)d_in[0];
  const float* attr = (const float*)d_in[1];
  const float* u    = (const float*)d_in[2];
  const int*   ei   = (const int*)d_in[3];
  const int*   rank = (const int*)d_in[4];
  const int* rowA = ei;
  const int* colA = ei + NE;
  float* outF = (float*)d_out;

  // workspace layout (4B elements)
  int* rcnt   = (int*)d_ws;          // NN
  int* cursor = rcnt + NN;           // NN
  int* rptr   = cursor + NN;         // NN+1
  int* ebuf   = rptr + NN + 1;       // NE
  int* misA   = ebuf + NE;           // NN
  int* covA   = misA + NN;           // NN
  int* nbA    = covA + NN;           // NN
  int* clA    = nbA + NN;            // NN
  int* unc    = clA + NN;            // MIS_ITERS
  int* one_   = unc + MIS_ITERS;     // 1
  float* degA = (float*)(one_ + 1);  // NN
  float* cntF = degA + NN;           // NN

  hipMemsetAsync(d_out, 0, (size_t)out_size * sizeof(float), stream);

  dim3 blk(256);
  dim3 gN((NN + 255) / 256);
  dim3 gE((NE + 255) / 256);
  dim3 gND((NN * DD + 255) / 256);
  dim3 gR((NN + 3) / 4);  // one wave per row, 4 waves/block

  k_init<<<gN, blk, 0, stream>>>(rcnt, cursor, misA, covA, nbA, unc, one_, cntF);
  k_hist<<<gE, blk, 0, stream>>>(rowA, rcnt);
  k_scan<<<1, 1024, 0, stream>>>(rcnt, rptr);
  k_fill<<<gE, blk, 0, stream>>>(rowA, rptr, cursor, ebuf);
  k_rowprep<<<gR, blk, 0, stream>>>(ebuf, rptr, colA, attr, degA);

  for (int i = 0; i < MIS_ITERS; i++) {
    const int* gate = (i == 0) ? one_ : (unc + (i - 1));
    k_emin<<<gE, blk, 0, stream>>>(gate, rowA, colA, covA, rank, nbA);
    k_node1<<<gN, blk, 0, stream>>>(gate, rank, nbA, misA, covA, unc + i);
    k_ecov<<<gE, blk, 0, stream>>>(gate, rowA, colA, misA, covA);
  }

  k_cluster<<<gN, blk, 0, stream>>>(rptr, ebuf, colA, attr, degA, misA, u, clA);
  k_final<<<gN, blk, 0, stream>>>(misA, clA, outF, cntF);
  k_pool<<<gND, blk, 0, stream>>>(x, clA, outF);
  k_div<<<gND, blk, 0, stream>>>(cntF, outF);
  k_adj<<<gE, blk, 0, stream>>>(rowA, colA, attr, clA, outF);
}